// Round 3
// baseline (396.148 us; speedup 1.0000x reference)
//
#include <hip/hip_runtime.h>

#define NEG_SLOPE 0.2f

__device__ __forceinline__ float leaky(float v) { return v > 0.f ? v : NEG_SLOPE * v; }
__device__ __forceinline__ float relu_f(float v) { return v > 0.f ? v : 0.f; }

// Thread layout (256 threads = 4 waves per block, 128 samples per block):
//   GAT phase : wave w, lane l -> sample pair = (w>>1)*64 + l, graph g = w&1
//               (g is WAVE-UNIFORM -> no divergence on the feature-build branch,
//                weight indices scalar)
//   MLP phase : s = tid&127 (sample), half = tid>>7 (hidden 0..63 / 64..127;
//               wave-uniform -> W1/W2 indices stay scalar)
// LDS: 128 rows x 33 dwords (pad -> <=2-way bank aliasing, free), reused for
// h-exchange then o-partial combine.
__global__ __launch_bounds__(256)
__attribute__((amdgpu_waves_per_eu(4)))
void scl_fused_kernel(
    const float* __restrict__ agent_pos, const float* __restrict__ agent_vel,
    const float* __restrict__ rel_lm, const float* __restrict__ other_pos,
    const float* __restrict__ lm_pos,
    const float* __restrict__ Wl, const float* __restrict__ bl,
    const float* __restrict__ Wr, const float* __restrict__ br,
    const float* __restrict__ We, const float* __restrict__ att,
    const float* __restrict__ bias,
    const float* __restrict__ W1, const float* __restrict__ b1,
    const float* __restrict__ W2, const float* __restrict__ b2,
    float* __restrict__ out, int Btot)
{
    __shared__ float lds[128 * 33];

    const int tid  = threadIdx.x;
    const int lane = tid & 63;
    const int wav  = tid >> 6;
    const int g    = wav & 1;                  // wave-uniform graph id
    const int pair = ((wav >> 1) << 6) | lane; // 0..127 sample-in-block
    int b = blockIdx.x * 128 + pair;
    if (b >= Btot) b = Btot - 1;               // clamp reads; barriers stay uniform

    const int o0[3] = {1, 0, 0};
    const int o1[3] = {2, 2, 1};

    // ---- positions (wave-uniform branch) ----
    float px[3], py[3];
    if (g == 0) {
#pragma unroll
        for (int j = 0; j < 3; ++j) {
            px[j] = agent_pos[b * 6 + 2 * j];
            py[j] = agent_pos[b * 6 + 2 * j + 1];
        }
    } else {
#pragma unroll
        for (int m = 0; m < 3; ++m) {
            px[m] = lm_pos[b * 18 + 2 * m];
            py[m] = lm_pos[b * 18 + 2 * m + 1];
        }
    }

    // ---- pairwise distances (symmetric: 3 scalars) ----
    float d01, d02, d12;
    {
        float dx, dy, sq;
        dx = px[0] - px[1]; dy = py[0] - py[1]; sq = dx * dx + dy * dy;
        d01 = sq > 0.f ? sqrtf(sq) : 0.f;
        dx = px[0] - px[2]; dy = py[0] - py[2]; sq = dx * dx + dy * dy;
        d02 = sq > 0.f ? sqrtf(sq) : 0.f;
        dx = px[1] - px[2]; dy = py[1] - py[2]; sq = dx * dx + dy * dy;
        d12 = sq > 0.f ? sqrtf(sq) : 0.f;
    }

    // ---- xl = x@Wl+bl, xr = x@Wr+br (xf transient per node) ----
    float xl[3][16], xr[3][16];
#pragma unroll
    for (int j = 0; j < 3; ++j) {
        float xf[14];
        if (g == 0) {
            xf[0] = px[j]; xf[1] = py[j];
            xf[2] = agent_vel[b * 6 + 2 * j];
            xf[3] = agent_vel[b * 6 + 2 * j + 1];
#pragma unroll
            for (int k = 0; k < 6; ++k) xf[4 + k] = rel_lm[b * 18 + j * 6 + k];
#pragma unroll
            for (int k = 0; k < 4; ++k) xf[10 + k] = other_pos[b * 12 + j * 4 + k];
        } else {
            xf[0] = px[j]; xf[1] = py[j];
            xf[2] = 0.f;   xf[3] = 0.f;
#pragma unroll
            for (int m = 0; m < 3; ++m) {
                xf[4 + 2 * m] = px[m] - px[j];
                xf[5 + 2 * m] = py[m] - py[j];
            }
            const int a = o0[j], c2 = o1[j];
            xf[10] = px[a]  - px[j]; xf[11] = py[a]  - py[j];
            xf[12] = px[c2] - px[j]; xf[13] = py[c2] - py[j];
        }
#pragma unroll
        for (int c = 0; c < 16; ++c) { xl[j][c] = bl[c]; xr[j][c] = br[c]; }
#pragma unroll
        for (int k = 0; k < 14; ++k) {
#pragma unroll
            for (int c = 0; c < 16; ++c) {
                xl[j][c] = fmaf(xf[k], Wl[k * 16 + c], xl[j][c]);
                xr[j][c] = fmaf(xf[k], Wr[k * 16 + c], xr[j][c]);
            }
        }
    }

    // ---- per-target logits -> softmax -> pooled accumulate (no lg array) ----
    float hs[16];
#pragma unroll
    for (int c = 0; c < 16; ++c) hs[c] = 0.f;

#pragma unroll
    for (int i = 0; i < 3; ++i) {
        float l3[3];
#pragma unroll
        for (int j = 0; j < 3; ++j) {
            float axv, ayv, adv;
            if (i == j) {
                const int a = o0[i], c2 = o1[i];
                axv = 0.5f * (px[a] + px[c2]) - px[i];
                ayv = 0.5f * (py[a] + py[c2]) - py[i];
                // mean of the two incoming non-self distances at node i
                const float dA = (i == 0) ? d01 : ((i == 1) ? d01 : d02);   // d(o0[i], i)
                const float dB = (i == 0) ? d02 : ((i == 1) ? d12 : d12);   // d(o1[i], i)
                adv = 0.5f * (dA + dB);
            } else {
                axv = px[j] - px[i];
                ayv = py[j] - py[i];
                adv = ((i == 0 && j == 1) || (i == 1 && j == 0)) ? d01
                    : ((i == 0 && j == 2) || (i == 2 && j == 0)) ? d02 : d12;
            }
            float acc = 0.f;
#pragma unroll
            for (int c = 0; c < 16; ++c) {
                float gg = xl[j][c] + xr[i][c];
                gg = fmaf(axv, We[c], gg);
                gg = fmaf(ayv, We[16 + c], gg);
                gg = fmaf(adv, We[32 + c], gg);
                acc = fmaf(leaky(gg), att[c], acc);
            }
            l3[j] = acc;
        }
        float m = fmaxf(l3[0], fmaxf(l3[1], l3[2]));
        float e0 = __expf(l3[0] - m);
        float e1 = __expf(l3[1] - m);
        float e2 = __expf(l3[2] - m);
        float inv = __builtin_amdgcn_rcpf(e0 + e1 + e2);
        float a0 = e0 * inv, a1 = e1 * inv, a2 = e2 * inv;
#pragma unroll
        for (int c = 0; c < 16; ++c) {
            float v = fmaf(a0, xl[0][c], fmaf(a1, xl[1][c], fmaf(a2, xl[2][c], bias[c])));
            hs[c] += relu_f(v);
        }
    }

    // ---- exchange pooled halves: h[0..15]=agent(g0), h[16..31]=objective(g1) ----
    __syncthreads();
#pragma unroll
    for (int c = 0; c < 16; ++c) lds[pair * 33 + g * 16 + c] = hs[c];
    __syncthreads();

    const int s    = tid & 127;
    const int half = tid >> 7;         // wave-uniform -> W1/W2 indices stay scalar
    float h[32];
#pragma unroll
    for (int k = 0; k < 32; ++k) h[k] = lds[s * 33 + k];
    __syncthreads();                   // all reads done before o-partial overwrite

    // ---- MLP: this thread does hidden units [half*64, half*64+64) ----
    float o[32];
#pragma unroll
    for (int c = 0; c < 32; ++c) o[c] = 0.f;

#pragma unroll
    for (int hc = 0; hc < 4; ++hc) {
        const int base = half * 64 + hc * 16;
        float z[16];
#pragma unroll
        for (int u = 0; u < 16; ++u) z[u] = b1[base + u];
#pragma unroll
        for (int k = 0; k < 32; ++k) {
#pragma unroll
            for (int u = 0; u < 16; ++u)
                z[u] = fmaf(h[k], W1[k * 128 + base + u], z[u]);
        }
#pragma unroll
        for (int u = 0; u < 16; ++u) {
            float zz = relu_f(z[u]);
#pragma unroll
            for (int c = 0; c < 32; ++c)
                o[c] = fmaf(zz, W2[(base + u) * 32 + c], o[c]);
        }
    }

    // ---- combine halves: half1 writes partials, half0 adds + stores ----
    if (half == 1) {
#pragma unroll
        for (int c = 0; c < 32; ++c) lds[s * 33 + c] = o[c];
    }
    __syncthreads();
    if (half == 0) {
        const int bS = blockIdx.x * 128 + s;
        if (bS < Btot) {
#pragma unroll
            for (int c = 0; c < 32; ++c) o[c] += lds[s * 33 + c] + b2[c];
#pragma unroll
            for (int q = 0; q < 8; ++q) {
                float4 v = make_float4(o[q * 4 + 0], o[q * 4 + 1], o[q * 4 + 2], o[q * 4 + 3]);
                reinterpret_cast<float4*>(out)[bS * 8 + q] = v;
            }
        }
    }
}

extern "C" void kernel_launch(void* const* d_in, const int* in_sizes, int n_in,
                              void* d_out, int out_size, void* d_ws, size_t ws_size,
                              hipStream_t stream) {
    const float* agent_pos = (const float*)d_in[0];
    const float* agent_vel = (const float*)d_in[1];
    const float* rel_lm    = (const float*)d_in[2];
    const float* other_pos = (const float*)d_in[3];
    const float* lm_pos    = (const float*)d_in[4];
    const float* Wl   = (const float*)d_in[5];
    const float* bl   = (const float*)d_in[6];
    const float* Wr   = (const float*)d_in[7];
    const float* br   = (const float*)d_in[8];
    const float* We   = (const float*)d_in[9];
    const float* att  = (const float*)d_in[10];
    const float* bias = (const float*)d_in[11];
    const float* W1   = (const float*)d_in[12];
    const float* b1   = (const float*)d_in[13];
    const float* W2   = (const float*)d_in[14];
    const float* b2   = (const float*)d_in[15];
    float* out = (float*)d_out;

    int B = in_sizes[0] / 6;                  // agent_pos is [B,3,2]
    int samplesPerBlock = 128;
    int grid = (B + samplesPerBlock - 1) / samplesPerBlock;
    scl_fused_kernel<<<grid, 256, 0, stream>>>(
        agent_pos, agent_vel, rel_lm, other_pos, lm_pos,
        Wl, bl, Wr, br, We, att, bias, W1, b1, W2, b2, out, B);
}

// Round 4
// 174.609 us; speedup vs baseline: 2.2688x; 2.2688x over previous
//
#include <hip/hip_runtime.h>

#define NEG_SLOPE 0.2f

__device__ __forceinline__ float leaky(float v) { return v > 0.f ? v : NEG_SLOPE * v; }
__device__ __forceinline__ float relu_f(float v) { return v > 0.f ? v : 0.f; }

// Thread layout (256 threads = 4 waves per block, 128 samples per block):
//   GAT phase : wave w, lane l -> sample pair = (w>>1)*64 + l, graph g = w&1
//               (g wave-uniform via readfirstlane -> uniform branch, scalar weights)
//   MLP phase : s = tid&127 (sample), half = readfirstlane(tid>>7)
//               (uniform -> W1/W2/b1 indices stay SGPR -> s_load)
// LDS: 128 rows x 33 dwords (pad -> 2-way bank aliasing = free), reused for
// h-exchange then o-partial combine.
// waves_per_eu(4,4): pin BOTH bounds -> 128-VGPR budget, no spill-for-occupancy
// (min-only variants made the allocator spill down to 64 VGPR; R2/R3 lesson).
__global__ __launch_bounds__(256)
__attribute__((amdgpu_waves_per_eu(4, 4)))
void scl_fused_kernel(
    const float* __restrict__ agent_pos, const float* __restrict__ agent_vel,
    const float* __restrict__ rel_lm, const float* __restrict__ other_pos,
    const float* __restrict__ lm_pos,
    const float* __restrict__ Wl, const float* __restrict__ bl,
    const float* __restrict__ Wr, const float* __restrict__ br,
    const float* __restrict__ We, const float* __restrict__ att,
    const float* __restrict__ bias,
    const float* __restrict__ W1, const float* __restrict__ b1,
    const float* __restrict__ W2, const float* __restrict__ b2,
    float* __restrict__ out, int Btot)
{
    __shared__ float lds[128 * 33];

    const int tid  = threadIdx.x;
    const int lane = tid & 63;
    const int wav  = tid >> 6;
    const int g    = __builtin_amdgcn_readfirstlane(wav & 1);  // uniform graph id
    const int pair = ((wav >> 1) << 6) | lane;                 // 0..127 sample-in-block
    int b = blockIdx.x * 128 + pair;
    if (b >= Btot) b = Btot - 1;               // clamp reads; barriers stay uniform

    const int o0[3] = {1, 0, 0};
    const int o1[3] = {2, 2, 1};

    // ---- positions (uniform branch, vector loads) ----
    float px[3], py[3];
    if (g == 0) {
        const float2* ap = reinterpret_cast<const float2*>(agent_pos + b * 6);
#pragma unroll
        for (int j = 0; j < 3; ++j) { px[j] = ap[j].x; py[j] = ap[j].y; }
    } else {
        const float2* lp = reinterpret_cast<const float2*>(lm_pos + b * 18);
#pragma unroll
        for (int m = 0; m < 3; ++m) { px[m] = lp[m].x; py[m] = lp[m].y; }
    }

    // ---- pairwise distances (symmetric: 3 scalars) ----
    float d01, d02, d12;
    {
        float dx, dy, sq;
        dx = px[0] - px[1]; dy = py[0] - py[1]; sq = dx * dx + dy * dy;
        d01 = sq > 0.f ? sqrtf(sq) : 0.f;
        dx = px[0] - px[2]; dy = py[0] - py[2]; sq = dx * dx + dy * dy;
        d02 = sq > 0.f ? sqrtf(sq) : 0.f;
        dx = px[1] - px[2]; dy = py[1] - py[2]; sq = dx * dx + dy * dy;
        d12 = sq > 0.f ? sqrtf(sq) : 0.f;
    }

    // ---- xl = x@Wl+bl, xr = x@Wr+br (xf transient per node) ----
    float xl[3][16], xr[3][16];
#pragma unroll
    for (int j = 0; j < 3; ++j) {
        float xf[14];
        if (g == 0) {
            const float2 vel = reinterpret_cast<const float2*>(agent_vel + b * 6)[j];
            const float2* rl = reinterpret_cast<const float2*>(rel_lm + b * 18 + j * 6);
            const float4 op  = reinterpret_cast<const float4*>(other_pos + b * 12)[j];
            xf[0] = px[j]; xf[1] = py[j];
            xf[2] = vel.x; xf[3] = vel.y;
            xf[4] = rl[0].x; xf[5] = rl[0].y;
            xf[6] = rl[1].x; xf[7] = rl[1].y;
            xf[8] = rl[2].x; xf[9] = rl[2].y;
            xf[10] = op.x; xf[11] = op.y; xf[12] = op.z; xf[13] = op.w;
        } else {
            xf[0] = px[j]; xf[1] = py[j];
            xf[2] = 0.f;   xf[3] = 0.f;
#pragma unroll
            for (int m = 0; m < 3; ++m) {
                xf[4 + 2 * m] = px[m] - px[j];
                xf[5 + 2 * m] = py[m] - py[j];
            }
            const int a = o0[j], c2 = o1[j];
            xf[10] = px[a]  - px[j]; xf[11] = py[a]  - py[j];
            xf[12] = px[c2] - px[j]; xf[13] = py[c2] - py[j];
        }
#pragma unroll
        for (int c = 0; c < 16; ++c) { xl[j][c] = bl[c]; xr[j][c] = br[c]; }
#pragma unroll
        for (int k = 0; k < 14; ++k) {
#pragma unroll
            for (int c = 0; c < 16; ++c) {
                xl[j][c] = fmaf(xf[k], Wl[k * 16 + c], xl[j][c]);
                xr[j][c] = fmaf(xf[k], Wr[k * 16 + c], xr[j][c]);
            }
        }
    }

    // ---- ALL logits first (xr dies here, before hs goes live) ----
    float lg[3][3];
#pragma unroll
    for (int i = 0; i < 3; ++i) {
#pragma unroll
        for (int j = 0; j < 3; ++j) {
            float axv, ayv, adv;
            if (i == j) {
                const int a = o0[i], c2 = o1[i];
                axv = 0.5f * (px[a] + px[c2]) - px[i];
                ayv = 0.5f * (py[a] + py[c2]) - py[i];
                const float dA = (i == 0) ? d01 : ((i == 1) ? d01 : d02);
                const float dB = (i == 0) ? d02 : ((i == 1) ? d12 : d12);
                adv = 0.5f * (dA + dB);
            } else {
                axv = px[j] - px[i];
                ayv = py[j] - py[i];
                adv = ((i == 0 && j == 1) || (i == 1 && j == 0)) ? d01
                    : ((i == 0 && j == 2) || (i == 2 && j == 0)) ? d02 : d12;
            }
            float acc = 0.f;
#pragma unroll
            for (int c = 0; c < 16; ++c) {
                float gg = xl[j][c] + xr[i][c];
                gg = fmaf(axv, We[c], gg);
                gg = fmaf(ayv, We[16 + c], gg);
                gg = fmaf(adv, We[32 + c], gg);
                acc = fmaf(leaky(gg), att[c], acc);
            }
            lg[j][i] = acc;
        }
    }

    // ---- softmax per target + weighted sum + pooled relu-sum ----
    float hs[16];
#pragma unroll
    for (int c = 0; c < 16; ++c) hs[c] = 0.f;
#pragma unroll
    for (int i = 0; i < 3; ++i) {
        float m = fmaxf(lg[0][i], fmaxf(lg[1][i], lg[2][i]));
        float e0 = __expf(lg[0][i] - m);
        float e1 = __expf(lg[1][i] - m);
        float e2 = __expf(lg[2][i] - m);
        float inv = __builtin_amdgcn_rcpf(e0 + e1 + e2);
        float a0 = e0 * inv, a1 = e1 * inv, a2 = e2 * inv;
#pragma unroll
        for (int c = 0; c < 16; ++c) {
            float v = fmaf(a0, xl[0][c], fmaf(a1, xl[1][c], fmaf(a2, xl[2][c], bias[c])));
            hs[c] += relu_f(v);
        }
    }

    // ---- exchange pooled halves: h[0..15]=agent(g0), h[16..31]=objective(g1) ----
    __syncthreads();
#pragma unroll
    for (int c = 0; c < 16; ++c) lds[pair * 33 + g * 16 + c] = hs[c];
    __syncthreads();

    const int s    = tid & 127;
    const int half = __builtin_amdgcn_readfirstlane(tid >> 7); // uniform -> scalar W1/W2
    float h[32];
#pragma unroll
    for (int k = 0; k < 32; ++k) h[k] = lds[s * 33 + k];
    __syncthreads();                   // all reads done before o-partial overwrite

    // ---- MLP: this thread does hidden units [half*64, half*64+64) ----
    float o[32];
#pragma unroll
    for (int c = 0; c < 32; ++c) o[c] = 0.f;

#pragma unroll
    for (int hc = 0; hc < 4; ++hc) {
        const int base = half * 64 + hc * 16;
        float z[16];
#pragma unroll
        for (int u = 0; u < 16; ++u) z[u] = b1[base + u];
#pragma unroll
        for (int k = 0; k < 32; ++k) {
#pragma unroll
            for (int u = 0; u < 16; ++u)
                z[u] = fmaf(h[k], W1[k * 128 + base + u], z[u]);
        }
#pragma unroll
        for (int u = 0; u < 16; ++u) {
            float zz = relu_f(z[u]);
#pragma unroll
            for (int c = 0; c < 32; ++c)
                o[c] = fmaf(zz, W2[(base + u) * 32 + c], o[c]);
        }
    }

    // ---- combine halves: half1 writes partials, half0 adds + stores ----
    if (half == 1) {
#pragma unroll
        for (int c = 0; c < 32; ++c) lds[s * 33 + c] = o[c];
    }
    __syncthreads();
    if (half == 0) {
        const int bS = blockIdx.x * 128 + s;
        if (bS < Btot) {
#pragma unroll
            for (int c = 0; c < 32; ++c) o[c] += lds[s * 33 + c] + b2[c];
#pragma unroll
            for (int q = 0; q < 8; ++q) {
                float4 v = make_float4(o[q * 4 + 0], o[q * 4 + 1], o[q * 4 + 2], o[q * 4 + 3]);
                reinterpret_cast<float4*>(out)[bS * 8 + q] = v;
            }
        }
    }
}

extern "C" void kernel_launch(void* const* d_in, const int* in_sizes, int n_in,
                              void* d_out, int out_size, void* d_ws, size_t ws_size,
                              hipStream_t stream) {
    const float* agent_pos = (const float*)d_in[0];
    const float* agent_vel = (const float*)d_in[1];
    const float* rel_lm    = (const float*)d_in[2];
    const float* other_pos = (const float*)d_in[3];
    const float* lm_pos    = (const float*)d_in[4];
    const float* Wl   = (const float*)d_in[5];
    const float* bl   = (const float*)d_in[6];
    const float* Wr   = (const float*)d_in[7];
    const float* br   = (const float*)d_in[8];
    const float* We   = (const float*)d_in[9];
    const float* att  = (const float*)d_in[10];
    const float* bias = (const float*)d_in[11];
    const float* W1   = (const float*)d_in[12];
    const float* b1   = (const float*)d_in[13];
    const float* W2   = (const float*)d_in[14];
    const float* b2   = (const float*)d_in[15];
    float* out = (float*)d_out;

    int B = in_sizes[0] / 6;                  // agent_pos is [B,3,2]
    int samplesPerBlock = 128;
    int grid = (B + samplesPerBlock - 1) / samplesPerBlock;
    scl_fused_kernel<<<grid, 256, 0, stream>>>(
        agent_pos, agent_vel, rel_lm, other_pos, lm_pos,
        Wl, bl, Wr, br, We, att, bias, W1, b1, W2, b2, out, B);
}